// Round 5
// baseline (572.318 us; speedup 1.0000x reference)
//
#include <hip/hip_runtime.h>
#include <cmath>

// Problem constants
#define NVOC 100
#define DIMN 200
#define LDA  256      // swizzled LDS stride for av/hv rows
#define DPD  204      // DIM + NADD
#define LDM  36       // stride for 32x32 LDS matrices
#define NTOT 8192
// grid = 256 molecules (1 block/CU), block = 512 threads (8 waves, 2/SIMD)
// Lane layout: w = t>>6 (wave, cols 32w..32w+31), c8 = lane&7 (col grp of 4),
// rq = lane>>3 (row quad). One W b128 load serves 4 rows x 4 cols = 16 FMA4.

#define FMA4(acc, s, wv) do { \
    (acc).x = fmaf((s),(wv).x,(acc).x); \
    (acc).y = fmaf((s),(wv).y,(acc).y); \
    (acc).z = fmaf((s),(wv).z,(acc).z); \
    (acc).w = fmaf((s),(wv).w,(acc).w); } while(0)

#define RELU4(v) do { \
    (v).x=fmaxf((v).x,0.f); (v).y=fmaxf((v).y,0.f); \
    (v).z=fmaxf((v).z,0.f); (v).w=fmaxf((v).w,0.f); } while(0)

// XOR swizzle: dword col c of row r lives at r*LDA + (c ^ 4*(r>>2)).
__device__ __forceinline__ int swz(int r, int c) {
    return (r << 8) + (c ^ (((r >> 2) & 7) << 2));
}

#define FMA_BLK(aa, w0, w1, w2, w3) do { \
    FMA4(acc[0],(aa)[0].x,(w0)); FMA4(acc[1],(aa)[1].x,(w0)); FMA4(acc[2],(aa)[2].x,(w0)); FMA4(acc[3],(aa)[3].x,(w0)); \
    FMA4(acc[0],(aa)[0].y,(w1)); FMA4(acc[1],(aa)[1].y,(w1)); FMA4(acc[2],(aa)[2].y,(w1)); FMA4(acc[3],(aa)[3].y,(w1)); \
    FMA4(acc[0],(aa)[0].z,(w2)); FMA4(acc[1],(aa)[1].z,(w2)); FMA4(acc[2],(aa)[2].z,(w2)); FMA4(acc[3],(aa)[3].z,(w2)); \
    FMA4(acc[0],(aa)[0].w,(w3)); FMA4(acc[1],(aa)[1].w,(w3)); FMA4(acc[2],(aa)[2].w,(w3)); FMA4(acc[3],(aa)[3].w,(w3)); } while(0)

#define LDS_A(dst, kk) do { \
    const int ks_ = (kk) ^ sw; \
    (dst)[0] = *(const float4*)&src[(r0+0)*LDA + ks_]; \
    (dst)[1] = *(const float4*)&src[(r0+1)*LDA + ks_]; \
    (dst)[2] = *(const float4*)&src[(r0+2)*LDA + ks_]; \
    (dst)[3] = *(const float4*)&src[(r0+3)*LDA + ks_]; } while(0)

// Software-pipelined GEMM: W prefetched 8k ahead (2 reg buffers, copy-free
// ping-pong), a prefetched 4k ahead. acc[j] = row r0+j, cols n0..n0+3.
__device__ __forceinline__ void gemm512(const float* src,
                                        const float* __restrict__ Wg,
                                        const float* __restrict__ bg,
                                        int r0, int n0, int sw, float4 acc[4])
{
    const float4 b = *(const float4*)&bg[n0];
    acc[0] = b; acc[1] = b; acc[2] = b; acc[3] = b;
    const float* Wp = Wg + n0;

    float4 wA0, wA1, wA2, wA3, wB0, wB1, wB2, wB3;
    float4 ab[4], an[4];
    // prologue: W rows 0..7, a cols 0..3
    wA0 = *(const float4*)(Wp);          wA1 = *(const float4*)(Wp + DIMN);
    wA2 = *(const float4*)(Wp + 2*DIMN); wA3 = *(const float4*)(Wp + 3*DIMN);
    wB0 = *(const float4*)(Wp + 4*DIMN); wB1 = *(const float4*)(Wp + 5*DIMN);
    wB2 = *(const float4*)(Wp + 6*DIMN); wB3 = *(const float4*)(Wp + 7*DIMN);
    LDS_A(ab, 0);

    const float* Wf = Wp + 8*DIMN;       // prefetch pointer (k+8 rows)
    #pragma unroll 1
    for (int k0 = 0; k0 < 192; k0 += 8) {
        // phase A: consume (ab, wA*) for k0; prefetch a[k0+4], W[k0+8..11]->wA*
        LDS_A(an, k0 + 4);
        FMA_BLK(ab, wA0, wA1, wA2, wA3);
        wA0 = *(const float4*)(Wf);          wA1 = *(const float4*)(Wf + DIMN);
        wA2 = *(const float4*)(Wf + 2*DIMN); wA3 = *(const float4*)(Wf + 3*DIMN);
        // phase B: consume (an, wB*) for k0+4; prefetch a[k0+8], W[k0+12..15]->wB*
        LDS_A(ab, k0 + 8);
        FMA_BLK(an, wB0, wB1, wB2, wB3);
        wB0 = *(const float4*)(Wf + 4*DIMN); wB1 = *(const float4*)(Wf + 5*DIMN);
        wB2 = *(const float4*)(Wf + 6*DIMN); wB3 = *(const float4*)(Wf + 7*DIMN);
        Wf += 8*DIMN;
    }
    // epilogue: k=192 (ab, wA*), prefetch a[196]; k=196 (an, wB*)
    LDS_A(an, 196);
    FMA_BLK(ab, wA0, wA1, wA2, wA3);
    FMA_BLK(an, wB0, wB1, wB2, wB3);
}

__global__ __launch_bounds__(512, 2)
void mgnn_kernel(const int*   __restrict__ atoms,
                 const float* __restrict__ dist,
                 const float* __restrict__ adducts,
                 const float* __restrict__ embed,
                 const float* __restrict__ gamma_tab,
                 const float* __restrict__ Waw,
                 const float* __restrict__ Wab,
                 const float* __restrict__ Wow,
                 const float* __restrict__ Wob,
                 const float* __restrict__ Wpw,
                 const float* __restrict__ Wpb,
                 const float* __restrict__ Wprw,
                 const float* __restrict__ Wprb,
                 float* __restrict__ out)
{
    __shared__ float  bufA[32*LDA];   // av / hv, swizzled (32 KB)
    __shared__ float  d2s [32*LDM];
    __shared__ float  Mts [32*LDM];   // Mts[j][r] = M[r][j]
    __shared__ float4 part4[64];      // norm partials [wave][rq]
    __shared__ float  scale_s[32];
    __shared__ float  red8[8];
    __shared__ int    atom_s[32];

    const int mol  = blockIdx.x;
    const int t    = threadIdx.x;
    const int base = mol * 32;
    const int w    = t >> 6;
    const int lane = t & 63;
    const int c8   = lane & 7;
    const int rq   = lane >> 3;
    const int r0   = rq * 4;
    const int n0   = w * 32 + c8 * 4;
    const bool act = (n0 < DIMN);     // wave 7 fully inactive
    const int sw   = (rq & 7) << 2;

    // ---- init ----
    if (t < 32) atom_s[t] = atoms[base + t];
    {
        const int j  = t >> 4;
        const int c2 = (t & 15) * 2;
        const float2 dd = *(const float2*)&dist[(size_t)(base + j) * NTOT + base + c2];
        float2 q; q.x = dd.x*dd.x; q.y = dd.y*dd.y;
        *(float2*)&d2s[j*LDM + c2] = q;
    }
    for (int idx = t; idx < 32*50; idx += 512) {
        const int r  = idx / 50;
        const int c4 = (idx % 50) * 4;
        const int a  = atoms[base + r];
        *(float4*)&bufA[swz(r, c4)] = *(const float4*)&embed[a*DIMN + c4];
    }
    __syncthreads();

    // ---- 6 hidden layers ----
    for (int l = 0; l < 6; ++l) {
        float4 acc[4];
        if (act)
            gemm512(bufA, Waw + l*DIMN*DIMN, Wab + l*DIMN, r0, n0, sw, acc);
        if (act) {
            #pragma unroll
            for (int i = 0; i < 4; ++i) RELU4(acc[i]);
        }
        __syncthreads();   // B1: all GEMM reads of bufA done
        if (act) {
            #pragma unroll
            for (int i = 0; i < 4; ++i)
                *(float4*)&bufA[swz(r0+i, n0)] = acc[i];   // hv in place
        }
        {   // Mts[j][r] = exp(-g[j]*d2[r][j]) (d2 symmetric)
            const int j  = t >> 4;
            const int rr = (t & 15) * 2;
            const float g = gamma_tab[l*NVOC + atom_s[j]];
            const float2 d = *(const float2*)&d2s[j*LDM + rr];
            Mts[j*LDM + rr]     = expf(-g*d.x);
            Mts[j*LDM + rr + 1] = expf(-g*d.y);
        }
        __syncthreads();   // B2: hv + Mts visible

        float4 p; p.x = p.y = p.z = p.w = 0.f;
        if (act) {
            // av_new = hv + M@hv, software-pipelined over jj (copy-free ping-pong)
            float4 m0, h0, m1, h1;
            m0 = *(const float4*)&Mts[0*LDM + r0];
            h0 = *(const float4*)&bufA[swz(0, n0)];
            #pragma unroll 1
            for (int jj = 0; jj < 30; jj += 2) {
                m1 = *(const float4*)&Mts[(jj+1)*LDM + r0];
                h1 = *(const float4*)&bufA[swz(jj+1, n0)];
                FMA4(acc[0], m0.x, h0); FMA4(acc[1], m0.y, h0);
                FMA4(acc[2], m0.z, h0); FMA4(acc[3], m0.w, h0);
                m0 = *(const float4*)&Mts[(jj+2)*LDM + r0];
                h0 = *(const float4*)&bufA[swz(jj+2, n0)];
                FMA4(acc[0], m1.x, h1); FMA4(acc[1], m1.y, h1);
                FMA4(acc[2], m1.z, h1); FMA4(acc[3], m1.w, h1);
            }
            m1 = *(const float4*)&Mts[31*LDM + r0];
            h1 = *(const float4*)&bufA[swz(31, n0)];
            FMA4(acc[0], m0.x, h0); FMA4(acc[1], m0.y, h0);
            FMA4(acc[2], m0.z, h0); FMA4(acc[3], m0.w, h0);
            FMA4(acc[0], m1.x, h1); FMA4(acc[1], m1.y, h1);
            FMA4(acc[2], m1.z, h1); FMA4(acc[3], m1.w, h1);

            p.x = acc[0].x*acc[0].x; p.x = fmaf(acc[0].y,acc[0].y,p.x);
            p.x = fmaf(acc[0].z,acc[0].z,p.x); p.x = fmaf(acc[0].w,acc[0].w,p.x);
            p.y = acc[1].x*acc[1].x; p.y = fmaf(acc[1].y,acc[1].y,p.y);
            p.y = fmaf(acc[1].z,acc[1].z,p.y); p.y = fmaf(acc[1].w,acc[1].w,p.y);
            p.z = acc[2].x*acc[2].x; p.z = fmaf(acc[2].y,acc[2].y,p.z);
            p.z = fmaf(acc[2].z,acc[2].z,p.z); p.z = fmaf(acc[2].w,acc[2].w,p.z);
            p.w = acc[3].x*acc[3].x; p.w = fmaf(acc[3].y,acc[3].y,p.w);
            p.w = fmaf(acc[3].z,acc[3].z,p.w); p.w = fmaf(acc[3].w,acc[3].w,p.w);
        }
        // reduce over the 8 col-groups (same rq, lanes differ in c8 only)
        #pragma unroll
        for (int m = 1; m < 8; m <<= 1) {
            p.x += __shfl_xor(p.x, m);
            p.y += __shfl_xor(p.y, m);
            p.z += __shfl_xor(p.z, m);
            p.w += __shfl_xor(p.w, m);
        }
        if (act && c8 == 0) part4[w*8 + rq] = p;
        __syncthreads();   // B3
        if (t < 32) {
            const float* pf = (const float*)part4;
            const int rqq = t >> 2, cm = t & 3;
            float s = 0.f;
            #pragma unroll
            for (int ww = 0; ww < 7; ++ww) s += pf[((ww*8 + rqq) << 2) + cm];
            scale_s[t] = 1.0f / fmaxf(sqrtf(s), 1e-12f);
        }
        __syncthreads();   // B4
        if (act) {
            const float4 sc4 = *(const float4*)&scale_s[r0];
            acc[0].x*=sc4.x; acc[0].y*=sc4.x; acc[0].z*=sc4.x; acc[0].w*=sc4.x;
            acc[1].x*=sc4.y; acc[1].y*=sc4.y; acc[1].z*=sc4.y; acc[1].w*=sc4.y;
            acc[2].x*=sc4.z; acc[2].y*=sc4.z; acc[2].z*=sc4.z; acc[2].w*=sc4.z;
            acc[3].x*=sc4.w; acc[3].y*=sc4.w; acc[3].z*=sc4.w; acc[3].w*=sc4.w;
            #pragma unroll
            for (int i = 0; i < 4; ++i)
                *(float4*)&bufA[swz(r0+i, n0)] = acc[i];   // av in place
        }
        __syncthreads();   // B5
    }

    // ---- 3 out layers: av = relu(av@W+b), in place ----
    for (int l = 0; l < 3; ++l) {
        float4 acc[4];
        if (act) {
            gemm512(bufA, Wow + l*DIMN*DIMN, Wob + l*DIMN, r0, n0, sw, acc);
            #pragma unroll
            for (int i = 0; i < 4; ++i) RELU4(acc[i]);
        }
        __syncthreads();
        if (act) {
            #pragma unroll
            for (int i = 0; i < 4; ++i)
                *(float4*)&bufA[swz(r0+i, n0)] = acc[i];
        }
        __syncthreads();
    }

    // ---- molecule sum + adduct concat (d2s reused for mv buffers) ----
    float* mv0 = d2s;
    float* mv1 = d2s + 256;
    if (t < DIMN) {
        float s = 0.f;
        #pragma unroll 4
        for (int r = 0; r < 32; ++r)
            s += bufA[(r << 8) + (t ^ (((r >> 2) & 7) << 2))];
        mv0[t] = s;
    } else if (t < DPD) {
        mv0[t] = adducts[mol*4 + (t - 200)];
    }
    __syncthreads();

    // ---- 3 pred layers on [204] vector ----
    float* pc = mv0;
    float* pn = mv1;
    for (int l = 0; l < 3; ++l) {
        if (t < DPD) {
            float acc = Wpb[l*DPD + t];
            const float* Wl = Wpw + l*DPD*DPD;
            #pragma unroll 4
            for (int k = 0; k < DPD; ++k)
                acc = fmaf(pc[k], Wl[k*DPD + t], acc);
            pn[t] = fmaxf(acc, 0.f);
        }
        __syncthreads();
        float* tp = pc; pc = pn; pn = tp;
    }

    // ---- final property head ----
    float v = (t < DPD) ? pc[t] * Wprw[t] : 0.f;
    #pragma unroll
    for (int m = 1; m < 64; m <<= 1) v += __shfl_xor(v, m);
    if (lane == 0) red8[w] = v;
    __syncthreads();
    if (t == 0) {
        float s = Wprb[0];
        #pragma unroll
        for (int ww = 0; ww < 8; ++ww) s += red8[ww];
        out[mol] = s;
    }
}

extern "C" void kernel_launch(void* const* d_in, const int* in_sizes, int n_in,
                              void* d_out, int out_size, void* d_ws, size_t ws_size,
                              hipStream_t stream) {
    const int*   atoms   = (const int*)  d_in[0];
    const float* dist    = (const float*)d_in[1];
    const float* adducts = (const float*)d_in[2];
    const float* embed   = (const float*)d_in[3];
    const float* gamma_t = (const float*)d_in[4];
    const float* Waw     = (const float*)d_in[5];
    const float* Wab     = (const float*)d_in[6];
    const float* Wow     = (const float*)d_in[7];
    const float* Wob     = (const float*)d_in[8];
    const float* Wpw     = (const float*)d_in[9];
    const float* Wpb     = (const float*)d_in[10];
    const float* Wprw    = (const float*)d_in[11];
    const float* Wprb    = (const float*)d_in[12];
    (void)in_sizes; (void)n_in; (void)d_ws; (void)ws_size; (void)out_size;

    mgnn_kernel<<<dim3(256), dim3(512), 0, stream>>>(
        atoms, dist, adducts, embed, gamma_t,
        Waw, Wab, Wow, Wob, Wpw, Wpb, Wprw, Wprb,
        (float*)d_out);
}

// Round 6
// 520.090 us; speedup vs baseline: 1.1004x; 1.1004x over previous
//
#include <hip/hip_runtime.h>
#include <cmath>

// Problem constants
#define NVOC 100
#define DIMN 200
#define LDA  256      // swizzled LDS stride for av/hv rows
#define DPD  204      // DIM + NADD
#define LDM  36       // stride for 32x32 LDS matrices
#define NTOT 8192
// grid = 256 molecules (1 block/CU), block = 896 threads = 14 waves (3.5/SIMD).
// K-split: kg = w/7 selects k-half (0..99 | 100..199), wc = w%7 selects cols
// 32wc..32wc+31. Thread tile = 4 rows x 4 cols (same W reuse as R4: one W b128
// serves 16 FMA4). Group 1 writes partial sums to bufP; group 0 combines.

#define FMA4(acc, s, wv) do { \
    (acc).x = fmaf((s),(wv).x,(acc).x); \
    (acc).y = fmaf((s),(wv).y,(acc).y); \
    (acc).z = fmaf((s),(wv).z,(acc).z); \
    (acc).w = fmaf((s),(wv).w,(acc).w); } while(0)

#define RELU4(v) do { \
    (v).x=fmaxf((v).x,0.f); (v).y=fmaxf((v).y,0.f); \
    (v).z=fmaxf((v).z,0.f); (v).w=fmaxf((v).w,0.f); } while(0)

// XOR swizzle: dword col c of row r lives at r*LDA + (c ^ 4*(r>>2)).
__device__ __forceinline__ int swz(int r, int c) {
    return (r << 8) + (c ^ (((r >> 2) & 7) << 2));
}

// Half-K GEMM: acc[j] = row r0+j, cols n0..n0+3, k in [kbase, kbase+100).
// bg == nullptr -> zero-init (partial-sum group). R4-style: compiler-scheduled
// (manual pipelining regressed in R5).
__device__ __forceinline__ void gemm_half(const float* src,
                                          const float* __restrict__ Wg,
                                          const float* __restrict__ bg,
                                          int kbase, int r0, int n0, int sw,
                                          float4 acc[4])
{
    if (bg) {
        const float4 b = *(const float4*)&bg[n0];
        acc[0] = b; acc[1] = b; acc[2] = b; acc[3] = b;
    } else {
        acc[0].x=acc[0].y=acc[0].z=acc[0].w=0.f;
        acc[1]=acc[0]; acc[2]=acc[0]; acc[3]=acc[0];
    }
    #pragma unroll 2
    for (int k0 = kbase; k0 < kbase + 100; k0 += 4) {
        const int ks = k0 ^ sw;
        const float4 a0 = *(const float4*)&src[(r0+0)*LDA + ks];
        const float4 a1 = *(const float4*)&src[(r0+1)*LDA + ks];
        const float4 a2 = *(const float4*)&src[(r0+2)*LDA + ks];
        const float4 a3 = *(const float4*)&src[(r0+3)*LDA + ks];
        const float* Wk = Wg + k0*DIMN + n0;
        const float4 w0 = *(const float4*)(Wk);
        const float4 w1 = *(const float4*)(Wk + DIMN);
        const float4 w2 = *(const float4*)(Wk + 2*DIMN);
        const float4 w3 = *(const float4*)(Wk + 3*DIMN);
        FMA4(acc[0],a0.x,w0); FMA4(acc[1],a1.x,w0); FMA4(acc[2],a2.x,w0); FMA4(acc[3],a3.x,w0);
        FMA4(acc[0],a0.y,w1); FMA4(acc[1],a1.y,w1); FMA4(acc[2],a2.y,w1); FMA4(acc[3],a3.y,w1);
        FMA4(acc[0],a0.z,w2); FMA4(acc[1],a1.z,w2); FMA4(acc[2],a2.z,w2); FMA4(acc[3],a3.z,w2);
        FMA4(acc[0],a0.w,w3); FMA4(acc[1],a1.w,w3); FMA4(acc[2],a2.w,w3); FMA4(acc[3],a3.w,w3);
    }
}

__global__ __launch_bounds__(896)
void mgnn_kernel(const int*   __restrict__ atoms,
                 const float* __restrict__ dist,
                 const float* __restrict__ adducts,
                 const float* __restrict__ embed,
                 const float* __restrict__ gamma_tab,
                 const float* __restrict__ Waw,
                 const float* __restrict__ Wab,
                 const float* __restrict__ Wow,
                 const float* __restrict__ Wob,
                 const float* __restrict__ Wpw,
                 const float* __restrict__ Wpb,
                 const float* __restrict__ Wprw,
                 const float* __restrict__ Wprb,
                 float* __restrict__ out)
{
    __shared__ float  bufA[32*LDA];   // av / hv, swizzled (32 KB)
    __shared__ float  bufP[32*LDA];   // k-half-1 partial sums, swizzled (32 KB)
    __shared__ float  d2s [32*LDM];
    __shared__ float  Mts [32*LDM];   // Mts[j][r] = M[r][j]
    __shared__ float4 part4[64];      // norm partials [wc][rq]
    __shared__ float  scale_s[32];
    __shared__ float  red16[16];
    __shared__ int    atom_s[32];
    // total ~74 KB

    const int mol  = blockIdx.x;
    const int t    = threadIdx.x;
    const int base = mol * 32;
    const int w    = t >> 6;          // wave 0..13
    const int lane = t & 63;
    const int kg   = (w >= 7);        // k-half group
    const int wc   = kg ? (w - 7) : w;  // col block 0..6
    const int c8   = lane & 7;
    const int rq   = lane >> 3;
    const int r0   = rq * 4;
    const int n0   = wc * 32 + c8 * 4;
    const bool act = (n0 < DIMN);     // wc==6: only c8<2 active
    const int sw   = (rq & 7) << 2;
    const int kbase = kg ? 100 : 0;

    // ---- init ----
    if (t < 32) atom_s[t] = atoms[base + t];
    if (t < 512) {
        const int j  = t >> 4;
        const int c2 = (t & 15) * 2;
        const float2 dd = *(const float2*)&dist[(size_t)(base + j) * NTOT + base + c2];
        float2 q; q.x = dd.x*dd.x; q.y = dd.y*dd.y;
        *(float2*)&d2s[j*LDM + c2] = q;
    }
    for (int idx = t; idx < 32*50; idx += 896) {
        const int r  = idx / 50;
        const int c4 = (idx % 50) * 4;
        const int a  = atoms[base + r];
        *(float4*)&bufA[swz(r, c4)] = *(const float4*)&embed[a*DIMN + c4];
    }
    __syncthreads();

    // ---- 6 hidden layers ----
    for (int l = 0; l < 6; ++l) {
        float4 acc[4];
        if (act)
            gemm_half(bufA, Waw + l*DIMN*DIMN, kg ? nullptr : (Wab + l*DIMN),
                      kbase, r0, n0, sw, acc);
        if (act && kg) {
            #pragma unroll
            for (int i = 0; i < 4; ++i)
                *(float4*)&bufP[swz(r0+i, n0)] = acc[i];
        }
        __syncthreads();   // B0: partials visible; all GEMM reads of bufA done
        if (act && !kg) {
            #pragma unroll
            for (int i = 0; i < 4; ++i) {
                const float4 pp = *(const float4*)&bufP[swz(r0+i, n0)];
                acc[i].x += pp.x; acc[i].y += pp.y;
                acc[i].z += pp.z; acc[i].w += pp.w;
                RELU4(acc[i]);
                *(float4*)&bufA[swz(r0+i, n0)] = acc[i];   // hv in place
            }
        }
        if (t < 512) {   // Mts[j][r] = exp(-g[j]*d2[r][j]) (d2 symmetric)
            const int j  = t >> 4;
            const int rr = (t & 15) * 2;
            const float g = gamma_tab[l*NVOC + atom_s[j]];
            const float2 d = *(const float2*)&d2s[j*LDM + rr];
            Mts[j*LDM + rr]     = expf(-g*d.x);
            Mts[j*LDM + rr + 1] = expf(-g*d.y);
        }
        __syncthreads();   // B2: hv + Mts visible

        float4 p; p.x = p.y = p.z = p.w = 0.f;
        if (act && !kg) {
            // av_new = hv + M@hv (acc holds this thread's relu'd hv tile)
            #pragma unroll 4
            for (int jj = 0; jj < 32; ++jj) {
                const float4 m4 = *(const float4*)&Mts[jj*LDM + r0];
                const float4 h4 = *(const float4*)&bufA[swz(jj, n0)];
                FMA4(acc[0], m4.x, h4);
                FMA4(acc[1], m4.y, h4);
                FMA4(acc[2], m4.z, h4);
                FMA4(acc[3], m4.w, h4);
            }
            p.x = acc[0].x*acc[0].x; p.x = fmaf(acc[0].y,acc[0].y,p.x);
            p.x = fmaf(acc[0].z,acc[0].z,p.x); p.x = fmaf(acc[0].w,acc[0].w,p.x);
            p.y = acc[1].x*acc[1].x; p.y = fmaf(acc[1].y,acc[1].y,p.y);
            p.y = fmaf(acc[1].z,acc[1].z,p.y); p.y = fmaf(acc[1].w,acc[1].w,p.y);
            p.z = acc[2].x*acc[2].x; p.z = fmaf(acc[2].y,acc[2].y,p.z);
            p.z = fmaf(acc[2].z,acc[2].z,p.z); p.z = fmaf(acc[2].w,acc[2].w,p.z);
            p.w = acc[3].x*acc[3].x; p.w = fmaf(acc[3].y,acc[3].y,p.w);
            p.w = fmaf(acc[3].z,acc[3].z,p.w); p.w = fmaf(acc[3].w,acc[3].w,p.w);
        }
        // reduce over the 8 col-groups (lanes differ only in c8 bits)
        #pragma unroll
        for (int m = 1; m < 8; m <<= 1) {
            p.x += __shfl_xor(p.x, m);
            p.y += __shfl_xor(p.y, m);
            p.z += __shfl_xor(p.z, m);
            p.w += __shfl_xor(p.w, m);
        }
        if (!kg && act && c8 == 0) part4[wc*8 + rq] = p;
        __syncthreads();   // B3
        if (t < 32) {
            const float* pf = (const float*)part4;
            const int rqq = t >> 2, cm = t & 3;
            float s = 0.f;
            #pragma unroll
            for (int ww = 0; ww < 7; ++ww) s += pf[((ww*8 + rqq) << 2) + cm];
            scale_s[t] = 1.0f / fmaxf(sqrtf(s), 1e-12f);
        }
        __syncthreads();   // B4
        if (act && !kg) {
            const float4 sc4 = *(const float4*)&scale_s[r0];
            acc[0].x*=sc4.x; acc[0].y*=sc4.x; acc[0].z*=sc4.x; acc[0].w*=sc4.x;
            acc[1].x*=sc4.y; acc[1].y*=sc4.y; acc[1].z*=sc4.y; acc[1].w*=sc4.y;
            acc[2].x*=sc4.z; acc[2].y*=sc4.z; acc[2].z*=sc4.z; acc[2].w*=sc4.z;
            acc[3].x*=sc4.w; acc[3].y*=sc4.w; acc[3].z*=sc4.w; acc[3].w*=sc4.w;
            #pragma unroll
            for (int i = 0; i < 4; ++i)
                *(float4*)&bufA[swz(r0+i, n0)] = acc[i];   // av in place
        }
        __syncthreads();   // B5
    }

    // ---- 3 out layers: av = relu(av@W+b), k-split + combine ----
    for (int l = 0; l < 3; ++l) {
        float4 acc[4];
        if (act)
            gemm_half(bufA, Wow + l*DIMN*DIMN, kg ? nullptr : (Wob + l*DIMN),
                      kbase, r0, n0, sw, acc);
        if (act && kg) {
            #pragma unroll
            for (int i = 0; i < 4; ++i)
                *(float4*)&bufP[swz(r0+i, n0)] = acc[i];
        }
        __syncthreads();   // partials visible; GEMM reads of bufA done
        if (act && !kg) {
            #pragma unroll
            for (int i = 0; i < 4; ++i) {
                const float4 pp = *(const float4*)&bufP[swz(r0+i, n0)];
                acc[i].x += pp.x; acc[i].y += pp.y;
                acc[i].z += pp.z; acc[i].w += pp.w;
                RELU4(acc[i]);
                *(float4*)&bufA[swz(r0+i, n0)] = acc[i];
            }
        }
        __syncthreads();   // new av visible to both groups
    }

    // ---- molecule sum + adduct concat (d2s reused for mv buffers) ----
    float* mv0 = d2s;
    float* mv1 = d2s + 256;
    if (t < DIMN) {
        float s = 0.f;
        #pragma unroll 4
        for (int r = 0; r < 32; ++r)
            s += bufA[(r << 8) + (t ^ (((r >> 2) & 7) << 2))];
        mv0[t] = s;
    } else if (t < DPD) {
        mv0[t] = adducts[mol*4 + (t - 200)];
    }
    __syncthreads();

    // ---- 3 pred layers on [204] vector ----
    float* pc = mv0;
    float* pn = mv1;
    for (int l = 0; l < 3; ++l) {
        if (t < DPD) {
            float acc = Wpb[l*DPD + t];
            const float* Wl = Wpw + l*DPD*DPD;
            #pragma unroll 4
            for (int k = 0; k < DPD; ++k)
                acc = fmaf(pc[k], Wl[k*DPD + t], acc);
            pn[t] = fmaxf(acc, 0.f);
        }
        __syncthreads();
        float* tp = pc; pc = pn; pn = tp;
    }

    // ---- final property head ----
    float v = (t < DPD) ? pc[t] * Wprw[t] : 0.f;
    #pragma unroll
    for (int m = 1; m < 64; m <<= 1) v += __shfl_xor(v, m);
    if (lane == 0) red16[w] = v;
    __syncthreads();
    if (t == 0) {
        float s = Wprb[0];
        #pragma unroll
        for (int ww = 0; ww < 14; ++ww) s += red16[ww];
        out[mol] = s;
    }
}

extern "C" void kernel_launch(void* const* d_in, const int* in_sizes, int n_in,
                              void* d_out, int out_size, void* d_ws, size_t ws_size,
                              hipStream_t stream) {
    const int*   atoms   = (const int*)  d_in[0];
    const float* dist    = (const float*)d_in[1];
    const float* adducts = (const float*)d_in[2];
    const float* embed   = (const float*)d_in[3];
    const float* gamma_t = (const float*)d_in[4];
    const float* Waw     = (const float*)d_in[5];
    const float* Wab     = (const float*)d_in[6];
    const float* Wow     = (const float*)d_in[7];
    const float* Wob     = (const float*)d_in[8];
    const float* Wpw     = (const float*)d_in[9];
    const float* Wpb     = (const float*)d_in[10];
    const float* Wprw    = (const float*)d_in[11];
    const float* Wprb    = (const float*)d_in[12];
    (void)in_sizes; (void)n_in; (void)d_ws; (void)ws_size; (void)out_size;

    mgnn_kernel<<<dim3(256), dim3(896), 0, stream>>>(
        atoms, dist, adducts, embed, gamma_t,
        Waw, Wab, Wow, Wob, Wpw, Wpb, Wprw, Wprb,
        (float*)d_out);
}